// Round 1
// baseline (193.737 us; speedup 1.0000x reference)
//
#include <hip/hip_runtime.h>
#include <stdint.h>

#define NPIX 65536
#define IGN (-255)
#define CAP 1022
// per-image scratch layout inside out[b*NPIX + ...] (ints 0..4095 = rows 0..15)
#define META_LI   2048
#define META_CF   2049
#define META_CB   2050
#define META_NROI 2051
#define META_FG   2052
#define META_BG   3074   // 2052 + 1022; 3074 + 1022 = 4096

// ---------------- threefry2x32 (exact JAX partitionable implementation) ----------------
__device__ __forceinline__ uint32_t rotl32(uint32_t v, uint32_t r){ return (v<<r)|(v>>(32u-r)); }

__device__ __forceinline__ void tf2x32(uint32_t k0, uint32_t k1, uint32_t x0, uint32_t x1,
                                       uint32_t &o0, uint32_t &o1){
  uint32_t k2 = k0 ^ k1 ^ 0x1BD11BDAu;
  x0 += k0; x1 += k1;
#define TFR(r) { x0 += x1; x1 = rotl32(x1,(r)); x1 ^= x0; }
  TFR(13u) TFR(15u) TFR(26u) TFR(6u)   x0 += k1; x1 += k2 + 1u;
  TFR(17u) TFR(29u) TFR(16u) TFR(24u)  x0 += k2; x1 += k0 + 2u;
  TFR(13u) TFR(15u) TFR(26u) TFR(6u)   x0 += k0; x1 += k1 + 3u;
  TFR(17u) TFR(29u) TFR(16u) TFR(24u)  x0 += k1; x1 += k2 + 4u;
  TFR(13u) TFR(15u) TFR(26u) TFR(6u)   x0 += k2; x1 += k0 + 5u;
#undef TFR
  o0 = x0; o1 = x1;
}

// pack score+index so that u64 max == (higher score, then lower index)
__device__ __forceinline__ unsigned long long packCand(uint32_t bits, uint32_t pix){
  float f = __uint_as_float((bits >> 9) | 0x3f800000u) - 1.0f;  // jax uniform [0,1)
  uint32_t u = __float_as_uint(f) ^ 0x80000000u;                // monotone map (f>=0)
  return ((unsigned long long)u << 32) | (unsigned long long)(0xFFFFFFFFu - pix);
}

// sorted-descending 10-element list, sentinel 0
__device__ __forceinline__ void t10_insert(unsigned long long* l, unsigned long long c){
  if (c > l[9]) {
    l[9] = c;
#pragma unroll
    for (int i = 9; i > 0; --i){
      unsigned long long a = l[i-1], b2 = l[i];
      if (b2 > a){ l[i-1] = b2; l[i] = a; }
    }
  }
}

// ---------------- KA: IGN fill (except scratch rows) + per-block hist partials ----------------
__global__ __launch_bounds__(256, 8)
void ka_hist_fill(const float* __restrict__ x, int* __restrict__ out){
  const int blk = blockIdx.x;
  const int b = blk >> 3, j8 = blk & 7;     // 8 blocks per image, 8192 px each
  const int tid = threadIdx.x;
  const float4* x4 = (const float4*)(x + (size_t)b * NPIX) + j8 * 2048;
  int4* o4 = (int4*)(out + (size_t)b * NPIX) + j8 * 2048;

  __shared__ uint32_t histR[1024];          // 256 bins x 4 lane-columns (conflict spread)
#pragma unroll
  for (int k = 0; k < 4; ++k) histR[tid + 256*k] = 0u;
  __syncthreads();

  const int4 f4 = make_int4(IGN, IGN, IGN, IGN);
  const uint32_t c4 = (uint32_t)(tid & 3);
#pragma unroll
  for (int jj = 0; jj < 8; ++jj){
    int p4 = tid + 256*jj;
    float4 v = x4[p4];
    // skip scratch rows (pixels 0..4095 of each image, i.e. j8==0 && jj<4)
    if (j8 != 0 || jj >= 4) o4[p4] = f4;
    uint32_t u0 = (uint32_t)min(max((int)floorf(v.x*255.0f),0),255);
    uint32_t u1 = (uint32_t)min(max((int)floorf(v.y*255.0f),0),255);
    uint32_t u2 = (uint32_t)min(max((int)floorf(v.z*255.0f),0),255);
    uint32_t u3 = (uint32_t)min(max((int)floorf(v.w*255.0f),0),255);
    atomicAdd(&histR[(u0<<2)|c4],1u); atomicAdd(&histR[(u1<<2)|c4],1u);
    atomicAdd(&histR[(u2<<2)|c4],1u); atomicAdd(&histR[(u3<<2)|c4],1u);
  }
  __syncthreads();
  uint32_t s = histR[4*tid] + histR[4*tid+1] + histR[4*tid+2] + histR[4*tid+3];
  out[(size_t)b*NPIX + j8*256 + tid] = (int)s;   // plain store: no zeroing pass needed
}

// ---------------- KB: per-image thresholds (hist sum -> scan -> Otsu -> Li) ----------------
__global__ __launch_bounds__(256, 2)
void kb_thresh(int* __restrict__ out){
  const int b = blockIdx.x;
  const int tid = threadIdx.x;
  int* meta = out + (size_t)b * NPIX;

  __shared__ float csum[256], cvsum[256];
  __shared__ int s_imin;
  __shared__ unsigned long long s_best;
  if (tid == 0){ s_imin = 255; s_best = 0ull; }
  __syncthreads();

  int h = 0;
#pragma unroll
  for (int j = 0; j < 8; ++j) h += meta[j*256 + tid];
  if (h) atomicMin(&s_imin, tid);
  __syncthreads();
  const float img_min = (float)s_imin;

  // exact-integer fp32 inclusive scans (any order bit-exact vs jnp.cumsum)
  csum[tid]  = (float)h;
  cvsum[tid] = (float)h * ((float)tid - img_min);
  __syncthreads();
  for (int off = 1; off < 256; off <<= 1){
    float a = 0.f, c2 = 0.f;
    if (tid >= off){ a = csum[tid-off]; c2 = cvsum[tid-off]; }
    __syncthreads();
    if (tid >= off){ csum[tid] += a; cvsum[tid] += c2; }
    __syncthreads();
  }

  // Otsu: per-bin var_b + 64-bit argmax (first max wins)
  {
    float s_tot_o = cvsum[255] + img_min * csum[255];
    if (tid < 255){
      float w0 = csum[tid];
      float w1 = 65536.0f - w0;
      float cs = cvsum[tid] + img_min * csum[tid];
      float m0 = cs / fmaxf(w0, 1e-12f);
      float m1 = (s_tot_o - cs) / fmaxf(w1, 1e-12f);
      float d = m0 - m1;
      float vb = (w0*w1) * (d*d);
      unsigned long long pk =
        ((unsigned long long)__float_as_uint(vb) << 32) | (unsigned long long)(255 - tid);
      atomicMax(&s_best, pk);
    }
  }
  __syncthreads();

  if (tid == 0){
    int bestIdx = 255 - (int)(s_best & 0xFFFFFFFFull);
    float otsu = fminf(fmaxf((float)bestIdx, 1.0f), 254.0f);
    float n_tot = csum[255], s_tot = cvsum[255];
    float t_curr = otsu - img_min, t_prev = t_curr + 10.0f;
    int it = 0;
    while (fabsf(t_curr - t_prev) > 0.5f && it < 64){
      int idx = min(max((int)floorf(t_curr + img_min), 0), 255);
      float n_back = csum[idx], s_back = cvsum[idx];
      float n_fore = n_tot - n_back, s_fore = s_tot - s_back;
      float mean_back = (n_back > 0.0f) ? (s_back / fmaxf(n_back, 1.0f)) : 0.0f;
      float mean_fore = s_fore / fmaxf(n_fore, 1.0f);
      float t_next = (mean_back - mean_fore) /
                     (logf(fmaxf(mean_back, 1e-12f)) - logf(fmaxf(mean_fore, 1e-12f)));
      if (mean_back < 1e-12f) t_next = mean_fore * 0.5f;
      t_prev = t_curr; t_curr = t_next; ++it;
    }
    float lit = t_curr + img_min;
    meta[META_LI] = __float_as_int(lit);
    // nroi = count(q > lit) = NPIX - csum[clamp(floor(lit))]   (lit >= img_min >= 0)
    int idx = min(max((int)floorf(lit), 0), 255);
    meta[META_NROI] = NPIX - (int)csum[idx];
    meta[META_CF] = 0;
    meta[META_CB] = 0;
  }
}

// ---------------- KC: threefry scoring, push candidate pixel indices ----------------
__global__ __launch_bounds__(256, 4)
void kc_score(const float* __restrict__ x, int* __restrict__ out){
  const int blk = blockIdx.x;
  const int b = blk >> 3, j8 = blk & 7;
  const int tid = threadIdx.x;
  int* meta = out + (size_t)b * NPIX;
  const float4* x4 = (const float4*)(x + (size_t)b * NPIX) + j8 * 2048;

  __shared__ uint32_t s_kw[4];
  __shared__ float s_lit;
  if (tid < 2){
    uint32_t o0, o1;
    tf2x32(0u, 1u, 0u, (uint32_t)(2*b + tid), o0, o1);
    s_kw[2*tid] = o0; s_kw[2*tid+1] = o1;
  }
  if (tid == 0) s_lit = __int_as_float(meta[META_LI]);
  __syncthreads();

  const float lit = s_lit;
  const uint32_t fk0 = s_kw[0], fk1 = s_kw[1], bk0 = s_kw[2], bk1 = s_kw[3];
  const uint32_t THRM = (0xFF000000u >> 9);  // mantissa-aligned cut, no tie straddle
#pragma unroll
  for (int jj = 0; jj < 8; ++jj){
    int p4 = tid + 256*jj;
    float4 v = x4[p4];
    uint32_t u0 = (uint32_t)min(max((int)floorf(v.x*255.0f),0),255);
    uint32_t u1 = (uint32_t)min(max((int)floorf(v.y*255.0f),0),255);
    uint32_t u2 = (uint32_t)min(max((int)floorf(v.z*255.0f),0),255);
    uint32_t u3 = (uint32_t)min(max((int)floorf(v.w*255.0f),0),255);
    uint32_t pk = u0 | (u1<<8) | (u2<<16) | (u3<<24);
    uint32_t pix0 = (uint32_t)(j8*8192 + 4*p4);
#pragma unroll
    for (int s = 0; s < 4; ++s){
      uint32_t q = (pk >> (8*s)) & 255u;
      bool r = ((float)q > lit);
      uint32_t o0, o1;
      tf2x32(r ? fk0 : bk0, r ? fk1 : bk1, 0u, pix0 + (uint32_t)s, o0, o1);
      uint32_t bits = o0 ^ o1;
      if ((bits >> 9) >= THRM){
        int r2 = r ? 0 : 1;
        int idx = atomicAdd(&meta[META_CF + r2], 1);
        if (idx < CAP) meta[(r2 ? META_BG : META_FG) + idx] = (int)(pix0 + (uint32_t)s);
      }
    }
  }
}

// ---------------- KD: score-rebuild, fail-check+fallback, top-10, scratch fill, patches --
__global__ __launch_bounds__(1024, 4)
void kd_final(const float* __restrict__ x, int* __restrict__ out){
  const int b = blockIdx.x;
  const int tid = threadIdx.x;
  int* meta = out + (size_t)b * NPIX;
  int* outb = meta;
  const float* img = x + (size_t)b * NPIX;

  __shared__ unsigned long long buf[2][CAP];
  __shared__ uint32_t s_kw[4];
  __shared__ int s_cnt[2], s_fail[2], s_np[2];
  __shared__ float s_lit;
  __shared__ int s_pr[2][10], s_pc[2][10];

  if (tid < 2){
    uint32_t o0, o1;
    tf2x32(0u, 1u, 0u, (uint32_t)(2*b + tid), o0, o1);
    s_kw[2*tid] = o0; s_kw[2*tid+1] = o1;
  }
  if (tid == 0){
    s_lit = __int_as_float(meta[META_LI]);
    int c0 = meta[META_CF], c1 = meta[META_CB];
    int nroi = meta[META_NROI];
    s_cnt[0] = c0; s_cnt[1] = c1;
    int m0r = nroi, m1r = NPIX - nroi;
    s_fail[0] = (c0 > CAP) || (c0 < 10 && c0 != m0r);
    s_fail[1] = (c1 > CAP) || (c1 < 10 && c1 != m1r);
  }
  __syncthreads();

  // rebuild packed candidates from pixel indices (identical tf2x32 -> identical packCand)
  {
    int r2 = tid >> 9, lane = tid & 511;
    uint32_t kk0 = s_kw[2*r2], kk1 = s_kw[2*r2+1];
    int n = min(s_cnt[r2], CAP);
    for (int i = lane; i < n; i += 512){
      uint32_t pix = (uint32_t)meta[(r2 ? META_BG : META_FG) + i];
      uint32_t o0, o1; tf2x32(kk0, kk1, 0u, pix, o0, o1);
      buf[r2][i] = packCand(o0 ^ o1, pix);
    }
  }
  __syncthreads();

  const float lit = s_lit;
  // fallback (statistically never runs; guarantees correctness)
  if (s_fail[0] || s_fail[1]){
    if (tid < 64){
      for (int r2 = 0; r2 < 2; ++r2){
        if (!s_fail[r2]) continue;
        uint32_t kk0 = s_kw[2*r2], kk1 = s_kw[2*r2+1];
        unsigned long long t[10];
#pragma unroll
        for (int i = 0; i < 10; ++i) t[i] = 0ull;
        for (int k2 = 0; k2 < 1024; ++k2){
          uint32_t pix = (uint32_t)(tid + 64*k2);
          float v = img[pix];
          int q = min(max((int)floorf(v*255.0f),0),255);
          bool r = ((float)q > lit);
          if (r != (r2 == 0)) continue;
          uint32_t o0, o1; tf2x32(kk0, kk1, 0u, pix, o0, o1);
          t10_insert(t, packCand(o0 ^ o1, pix));
        }
#pragma unroll
        for (int i = 0; i < 10; ++i) buf[r2][tid*10 + i] = t[i];
      }
    }
    __syncthreads();
    if (tid < 2 && s_fail[tid]){
      unsigned long long t[10];
#pragma unroll
      for (int i = 0; i < 10; ++i) t[i] = 0ull;
      for (int i = 0; i < 640; ++i) t10_insert(t, buf[tid][i]);
#pragma unroll
      for (int i = 0; i < 10; ++i) buf[tid][i] = t[i];
      s_cnt[tid] = 10;
    }
    __syncthreads();
  }

  // extract top-10 points (fg on thread 0, bg on thread 64, parallel waves)
  if (tid == 0 || tid == 64){
    int r2 = (tid == 0) ? 0 : 1;
    int n = min(s_cnt[r2], CAP);
    unsigned long long t[10];
#pragma unroll
    for (int i = 0; i < 10; ++i) t[i] = 0ull;
    for (int i = 0; i < n; ++i) t10_insert(t, buf[r2][i]);
    int np = 0;
    for (int i = 0; i < 10; ++i){
      if (t[i]){
        uint32_t pix = 0xFFFFFFFFu - (uint32_t)(t[i] & 0xFFFFFFFFull);
        s_pr[r2][np] = (int)(pix >> 8);
        s_pc[r2][np] = (int)(pix & 255u);
        ++np;
      }
    }
    s_np[r2] = np;
  }
  __syncthreads();

  // overwrite scratch rows with IGN (candidates already consumed)
  ((int4*)meta)[tid] = make_int4(IGN, IGN, IGN, IGN);   // 1024 * int4 = ints 0..4095
  __syncthreads();

  // write dilated seed patches (<=180 px); duplicates write identical values
  const int nfg = s_np[0], nbg = s_np[1];
  const int npts = nfg + nbg;
  if (tid < npts*9){
    int k = tid / 9, d = tid - k*9;
    int pr = (k < nfg) ? s_pr[0][k] : s_pr[1][k - nfg];
    int pc = (k < nfg) ? s_pc[0][k] : s_pc[1][k - nfg];
    pr += d/3 - 1; pc += d%3 - 1;
    if (pr >= 0 && pr < 256 && pc >= 0 && pc < 256){
      bool fgd = false, bgd = false;
      for (int i = 0; i < nfg; ++i) fgd |= (abs(pr - s_pr[0][i]) <= 1) && (abs(pc - s_pc[0][i]) <= 1);
      for (int i = 0; i < nbg; ++i) bgd |= (abs(pr - s_pr[1][i]) <= 1) && (abs(pc - s_pc[1][i]) <= 1);
      int val = (fgd && bgd) ? IGN : (fgd ? 1 : 0);
      outb[pr*256 + pc] = val;
    }
  }
}

extern "C" void kernel_launch(void* const* d_in, const int* in_sizes, int n_in,
                              void* d_out, int out_size, void* d_ws, size_t ws_size,
                              hipStream_t stream) {
  const float* x = (const float*)d_in[0];
  int* out = (int*)d_out;
  int B = in_sizes[0] / NPIX;
  ka_hist_fill<<<8*B, 256, 0, stream>>>(x, out);
  kb_thresh  <<<B,   256, 0, stream>>>(out);
  kc_score   <<<8*B, 256, 0, stream>>>(x, out);
  kd_final   <<<B,  1024, 0, stream>>>(x, out);
}